// Round 6
// baseline (362.557 us; speedup 1.0000x reference)
//
#include <hip/hip_runtime.h>
#include <math.h>

#define ROWS 8
#define NPAIRS 195
#define NTHREADS 256
#define ROW_OUT 258               // 63 copied + 195 distances
#define NLM 21
#define TILE_F (ROWS * ROW_OUT)   // 2064 floats = 8256 B
#define IN_F   (ROWS * 63)        // 504 floats = 2016 B
#define GRID 2048                 // 8 blocks/CU on 256 CUs

typedef float f32x4 __attribute__((ext_vector_type(4)));
typedef float f32x2 __attribute__((ext_vector_type(2)));

// ---- compile-time pair table, packed as (i | j<<16) ----
struct CodeTab { unsigned int c[NPAIRS]; };

constexpr CodeTab make_codes() {
    CodeTab t{};
    int n = 0;
    for (int a = 0; a < 20; ++a) {
        bool tip = (a == 4) || (a == 8) || (a == 12) || (a == 16) || (a == 19);
        int start = tip ? a + 1 : a + 2;
        for (int b = start; b < 21; ++b) {
            t.c[n] = (unsigned int)a | ((unsigned int)b << 16);
            ++n;
        }
    }
    return t;
}

__constant__ CodeTab CODES = make_codes();

__device__ __forceinline__ void scatter_tile(float* __restrict__ tile,
                                             float2* __restrict__ xy2,
                                             const f32x2 v, int t) {
    const int f = t * 2;
#pragma unroll
    for (int e = 0; e < 2; ++e) {
        const int g = f + e;
        const int row = g / 63;
        const int col = g - row * 63;
        tile[row * ROW_OUT + col] = v[e];
        const int lm = col / 3;
        const int c3 = col - lm * 3;
        if (c3 == 0) xy2[row * NLM + lm].x = v[e];
        else if (c3 == 1) xy2[row * NLM + lm].y = v[e];
    }
}

__device__ __forceinline__ void compute_dists(float* __restrict__ tile,
                                              const float2* __restrict__ xy2,
                                              int t) {
#pragma unroll
    for (int k = 0; k < 7; ++k) {
        const int idx = t + k * NTHREADS;
        if (idx < ROWS * NPAIRS) {
            const int row = idx / NPAIRS;
            const int p = idx - row * NPAIRS;
            const unsigned int c = CODES.c[p];
            const float2 a = xy2[row * NLM + (int)(c & 0xffu)];
            const float2 b = xy2[row * NLM + (int)(c >> 16)];
            const float dx = a.x - b.x;
            const float dy = a.y - b.y;
            tile[row * ROW_OUT + 63 + p] = sqrtf(dx * dx + dy * dy);
        }
    }
}

// in : [B, 63]  (21 landmarks x (x,y,z))
// out: [B, 258] = [copy of 63 | 195 pairwise 2D distances]
__global__ __launch_bounds__(NTHREADS, 8)
void HandKineticLayer_18545668784560_kernel(const float* __restrict__ in,
                                            float* __restrict__ out,
                                            int B) {
    __shared__ __align__(16) float tile[2][TILE_F];
    __shared__ float2 xy2[2][ROWS * NLM];

    const int t = threadIdx.x;
    const int ntiles = B / ROWS;               // full tiles

    // ---- prologue: load + scatter first tile into buffer 0 ----
    const int tile0 = blockIdx.x;
    if (tile0 < ntiles) {
        if (t < 252) {
            const f32x2* __restrict__ in2 =
                reinterpret_cast<const f32x2*>(in + (size_t)tile0 * IN_F);
            const f32x2 v = __builtin_nontemporal_load(&in2[t]);
            scatter_tile(tile[0], xy2[0], v, t);
        }
        __syncthreads();
    }

    // ---- pipelined main loop: prefetch(k+1) || compute(k); store(k); scatter(k+1) ----
    int i = 0;
    for (int tl = tile0; tl < ntiles; tl += GRID, ++i) {
        const int cur = i & 1;
        const int nxt = tl + GRID;
        f32x2 vn{};
        const bool have_next = (nxt < ntiles) && (t < 252);
        if (have_next) {
            const f32x2* __restrict__ in2 =
                reinterpret_cast<const f32x2*>(in + (size_t)nxt * IN_F);
            vn = __builtin_nontemporal_load(&in2[t]);   // in flight during compute+store
        }

        compute_dists(tile[cur], xy2[cur], t);
        __syncthreads();   // distances visible before store reads

        {
            const f32x4* __restrict__ tl4 =
                reinterpret_cast<const f32x4*>(&tile[cur][0]);
            f32x4* __restrict__ o4 =
                reinterpret_cast<f32x4*>(out + (size_t)tl * TILE_F);
#pragma unroll
            for (int k = t; k < TILE_F / 4; k += NTHREADS) {
                __builtin_nontemporal_store(tl4[k], &o4[k]);
            }
        }

        if (have_next) {
            scatter_tile(tile[cur ^ 1], xy2[cur ^ 1], vn, t);
        }
        __syncthreads();   // scatter visible for next compute; store reads drained
    }

    // ---- tail: partial tile (B % 8 != 0), one block, non-pipelined ----
    const int rem = B - ntiles * ROWS;
    if (rem > 0 && blockIdx.x == (unsigned)(ntiles % GRID)) {
        const int rowBase = ntiles * ROWS;
        const int nelem = rem * 63;
        for (int g = t; g < nelem; g += NTHREADS) {
            const float val = in[(size_t)rowBase * 63 + g];
            const int row = g / 63;
            const int col = g - row * 63;
            tile[0][row * ROW_OUT + col] = val;
            const int lm = col / 3;
            const int c3 = col - lm * 3;
            if (c3 == 0) xy2[0][row * NLM + lm].x = val;
            else if (c3 == 1) xy2[0][row * NLM + lm].y = val;
        }
        __syncthreads();
        const int total = rem * NPAIRS;
        for (int idx = t; idx < total; idx += NTHREADS) {
            const int row = idx / NPAIRS;
            const int p = idx - row * NPAIRS;
            const unsigned int c = CODES.c[p];
            const float2 a = xy2[0][row * NLM + (int)(c & 0xffu)];
            const float2 b = xy2[0][row * NLM + (int)(c >> 16)];
            const float dx = a.x - b.x;
            const float dy = a.y - b.y;
            tile[0][row * ROW_OUT + 63 + p] = sqrtf(dx * dx + dy * dy);
        }
        __syncthreads();
        const int nout = rem * ROW_OUT;
        for (int k = t; k < nout; k += NTHREADS) {
            out[(size_t)rowBase * ROW_OUT + k] = tile[0][k];
        }
    }
}

extern "C" void kernel_launch(void* const* d_in, const int* in_sizes, int n_in,
                              void* d_out, int out_size, void* d_ws, size_t ws_size,
                              hipStream_t stream) {
    const float* in = (const float*)d_in[0];
    float* out = (float*)d_out;
    const int B = in_sizes[0] / 63;
    hipLaunchKernelGGL(HandKineticLayer_18545668784560_kernel,
                       dim3(GRID), dim3(NTHREADS), 0, stream,
                       in, out, B);
}

// Round 8
// 306.198 us; speedup vs baseline: 1.1841x; 1.1841x over previous
//
#include <hip/hip_runtime.h>
#include <math.h>

#define ROWS 16
#define NPAIRS 195
#define NTHREADS 256
#define ROW_OUT 258               // out floats per row; LDS tile uses same stride
#define NLM 21
#define XY_PAD 24                 // xy2 row stride (float2)
#define TILE_F (ROWS * ROW_OUT)   // 4128 floats = 16512 B (exact out-tile image)
#define IN_F (ROWS * 63)
#define GRID 1024                 // 4 blocks/CU
#define NSTEPS 98                 // ceil(195/2) 2-pair steps

typedef float f32x4 __attribute__((ext_vector_type(4)));
typedef float f32x2 __attribute__((ext_vector_type(2)));

// barrier with LDS-only drain: do NOT wait for global (nt) stores to complete
#define LDS_BARRIER() asm volatile("s_waitcnt lgkmcnt(0)\n\ts_barrier" ::: "memory")

// ---- compile-time 2-pair step table ----
// step s covers pairs (2s, 2s+1). boundary steps always have i1==i0+1.
// fields: i0 | j0<<5 | i1<<10 | j1<<15 | fast<<20
struct StepTab { unsigned int m[NSTEPS]; };

constexpr StepTab make_steps() {
    int pi[NPAIRS] = {}; int pj[NPAIRS] = {};
    int n = 0;
    for (int a = 0; a < 20; ++a) {
        bool tip = (a==4)||(a==8)||(a==12)||(a==16)||(a==19);
        int start = tip ? a+1 : a+2;
        for (int b = start; b < 21; ++b) { pi[n]=a; pj[n]=b; ++n; }
    }
    StepTab t{};
    for (int s = 0; s < NSTEPS; ++s) {
        int p0 = 2*s; int p1 = 2*s+1 < NPAIRS ? 2*s+1 : NPAIRS-1;  // s=97 dup
        unsigned i0=pi[p0], j0=pj[p0], i1=pi[p1], j1=pj[p1];
        unsigned fast = (i0==i1 && j1==j0+1) ? 1u : 0u;
        t.m[s] = i0 | (j0<<5) | (i1<<10) | (j1<<15) | (fast<<20);
    }
    return t;
}

__constant__ StepTab STEPS = make_steps();

// scatter one input float4 (elements g=4t..4t+3) into tile + xy2
__device__ __forceinline__ void scatter_tile(float* __restrict__ tile,
                                             float2* __restrict__ xy2,
                                             const f32x4 v, int t) {
    const int f = t * 4;
    const int row0 = f / 63;
    const int col0 = f - row0 * 63;
    if (col0 <= 59) {
        // all 4 elements in one row: contiguous LDS stores (fusable)
        float* __restrict__ p = tile + row0 * ROW_OUT + col0;
        p[0]=v[0]; p[1]=v[1]; p[2]=v[2]; p[3]=v[3];
        float2* __restrict__ xr = xy2 + row0 * XY_PAD;
#pragma unroll
        for (int e = 0; e < 4; ++e) {
            const int col = col0 + e;
            const int lm = col / 3;
            const int c3 = col - lm * 3;
            if (c3 == 0) xr[lm].x = v[e];
            else if (c3 == 1) xr[lm].y = v[e];
        }
    } else {
#pragma unroll
        for (int e = 0; e < 4; ++e) {
            const int g = f + e;
            const int row = g / 63;
            const int col = g - row * 63;
            tile[row * ROW_OUT + col] = v[e];
            const int lm = col / 3;
            const int c3 = col - lm * 3;
            if (c3 == 0) xy2[row * XY_PAD + lm].x = v[e];
            else if (c3 == 1) xy2[row * XY_PAD + lm].y = v[e];
        }
    }
}

// row-per-lane-group distance phase: t>>4 = row, t&15 = q; steps s = q, q+16, ...
__device__ __forceinline__ void compute_dists(float* __restrict__ tile,
                                              const float2* __restrict__ xy2,
                                              int t) {
    const int r = t >> 4;
    const int q = t & 15;
    float* __restrict__ drow = tile + r * ROW_OUT + 63;
    const float2* __restrict__ xr = xy2 + r * XY_PAD;
    for (int s = q; s < NSTEPS; s += 16) {
        const unsigned m = STEPS.m[s];
        const int i0 = (int)(m & 31u);
        const int j0 = (int)((m >> 5) & 31u);
        const int j1 = (int)((m >> 15) & 31u);
        float2 a0, a1, b0, b1;
        if (m & (1u << 20)) {          // fast: same i, consecutive j -> read2_b64
            b0 = xr[j0]; b1 = xr[j0 + 1];
            a0 = xr[i0]; a1 = a0;
        } else {                       // slow: i1 == i0+1 by construction
            a0 = xr[i0]; a1 = xr[i0 + 1];
            b0 = xr[j0]; b1 = xr[j1];
        }
        const float dx0 = a0.x - b0.x, dy0 = a0.y - b0.y;
        const float dx1 = a1.x - b1.x, dy1 = a1.y - b1.y;
        const float d0 = __builtin_amdgcn_sqrtf(dx0*dx0 + dy0*dy0);
        const float d1 = __builtin_amdgcn_sqrtf(dx1*dx1 + dy1*dy1);
        drow[2*s]     = d0;            // adjacent -> ds_write2_b32
        drow[2*s + 1] = d1;            // s=97 d1: col 258 -> next row col 0?  NO:
                                       // 63+195=258 == ROW_OUT -> first elem of
                                       // next row's copy section. Must avoid!
    }
}

// stream tile -> out tile (contiguous, nt float4)
__device__ __forceinline__ void store_tile(const float* __restrict__ tile,
                                           float* __restrict__ outp, int t) {
#pragma unroll
    for (int k = t; k < TILE_F / 4; k += NTHREADS) {
        const f32x4 o = *(const f32x4*)(tile + 4 * k);   // ds_read_b128
        __builtin_nontemporal_store(o, (f32x4*)(outp + 4 * k));
    }
}

__global__ __launch_bounds__(NTHREADS, 4)
void HandKineticLayer_18545668784560_kernel(const float* __restrict__ in,
                                            float* __restrict__ out,
                                            int B) {
    // tile is an exact image of the 16x258 output tile (+8 pad floats for the
    // s=97 duplicate-write overhang on the LAST row: row 15 col 258)
    __shared__ __align__(16) float tile[2][TILE_F + 8];
    __shared__ float2 xy2[2][ROWS * XY_PAD];

    const int t = threadIdx.x;
    const int ntiles = B / ROWS;

    // ---- prologue ----
    const int tile0 = blockIdx.x;
    if (tile0 < ntiles) {
        if (t < 252) {
            const f32x4* __restrict__ in4 =
                reinterpret_cast<const f32x4*>(in + (size_t)tile0 * IN_F);
            const f32x4 v = __builtin_nontemporal_load(&in4[t]);
            scatter_tile(tile[0], xy2[0], v, t);
        }
        LDS_BARRIER();
    }

    // ---- main loop: prefetch(k+1) | compute(k); store(k); scatter(k+1) ----
    int i = 0;
    for (int tl = tile0; tl < ntiles; tl += GRID, ++i) {
        const int cur = i & 1;
        const int nxt = tl + GRID;
        f32x4 vn{};
        const bool have_next = (nxt < ntiles) && (t < 252);
        if (have_next) {
            const f32x4* __restrict__ in4 =
                reinterpret_cast<const f32x4*>(in + (size_t)nxt * IN_F);
            vn = __builtin_nontemporal_load(&in4[t]);
        }

        compute_dists(tile[cur], xy2[cur], t);
        LDS_BARRIER();                 // dists visible to store-readers
        // IMPORTANT: s=97's d1 writes tile[row*258 + 258] = next row's col 0,
        // clobbering the copy section -- EXCEPT we re-write it here? No:
        // store reads AFTER the clobber. Fix: rows 0..14's overhang must be
        // repaired. We repair by re-scattering col0 of rows 1..15 before store.
        if ((t & 15) == 1 && (t >> 4) >= 1) {
            // lane group q=1, rows 1..15: restore row r col 0 from xy2 (x of lm 0)
            const int r = t >> 4;
            tile[cur][r * ROW_OUT + 0] = xy2[cur][r * XY_PAD + 0].x;
        }
        LDS_BARRIER();

        store_tile(tile[cur], out + (size_t)tl * TILE_F, t);

        if (have_next) {
            scatter_tile(tile[cur ^ 1], xy2[cur ^ 1], vn, t);
        }
        LDS_BARRIER();                 // scatter visible; LDS reads of cur done
    }

    // ---- tail: partial tile (B % 16 != 0) ----
    const int rem = B - ntiles * ROWS;
    if (rem > 0 && blockIdx.x == (unsigned)(ntiles % GRID)) {
        const int rowBase = ntiles * ROWS;
        const int nelem = rem * 63;
        for (int g = t; g < nelem; g += NTHREADS) {
            const float val = in[(size_t)rowBase * 63 + g];
            const int row = g / 63;
            const int col = g - row * 63;
            tile[0][row * ROW_OUT + col] = val;
            const int lm = col / 3;
            const int c3 = col - lm * 3;
            if (c3 == 0) xy2[0][row * XY_PAD + lm].x = val;
            else if (c3 == 1) xy2[0][row * XY_PAD + lm].y = val;
        }
        __syncthreads();
        const int total = rem * NPAIRS;
        for (int idx = t; idx < total; idx += NTHREADS) {
            const int row = idx / NPAIRS;
            const int p = idx - row * NPAIRS;
            const unsigned m = STEPS.m[p >> 1];
            const int ii = (p & 1) ? (int)((m>>10)&31u) : (int)(m & 31u);
            const int jj = (p & 1) ? (int)((m>>15)&31u) : (int)((m>>5)&31u);
            const float2 a = xy2[0][row * XY_PAD + ii];
            const float2 b = xy2[0][row * XY_PAD + jj];
            const float dx = a.x - b.x, dy = a.y - b.y;
            tile[0][row * ROW_OUT + 63 + p] = __builtin_amdgcn_sqrtf(dx*dx + dy*dy);
        }
        __syncthreads();
        const int nout = rem * ROW_OUT;
        for (int k = t; k < nout; k += NTHREADS) {
            out[(size_t)rowBase * ROW_OUT + k] = tile[0][k];
        }
    }
}

extern "C" void kernel_launch(void* const* d_in, const int* in_sizes, int n_in,
                              void* d_out, int out_size, void* d_ws, size_t ws_size,
                              hipStream_t stream) {
    const float* in = (const float*)d_in[0];
    float* out = (float*)d_out;
    const int B = in_sizes[0] / 63;
    hipLaunchKernelGGL(HandKineticLayer_18545668784560_kernel,
                       dim3(GRID), dim3(NTHREADS), 0, stream,
                       in, out, B);
}

// Round 9
// 271.375 us; speedup vs baseline: 1.3360x; 1.1283x over previous
//
#include <hip/hip_runtime.h>
#include <math.h>

#define ROWS 16
#define NPAIRS 195
#define NTHREADS 256
#define ROW_OUT 258            // 63 copied + 195 distances
#define NLM 21
#define TILE_F (ROWS * ROW_OUT)   // 4128 floats = 16512 B (16B-aligned stride)
#define IN_F (ROWS * 63)
#define GRID 1024                 // 4 blocks/CU on 256 CUs

typedef float f32x4 __attribute__((ext_vector_type(4)));

// barrier with LDS-only drain: do NOT wait for outstanding global (nt) stores
#define LDS_BARRIER() asm volatile("s_waitcnt lgkmcnt(0)\n\ts_barrier" ::: "memory")

// ---- compile-time pair table, packed as (i | j<<16) ----
struct CodeTab { unsigned int c[NPAIRS]; };

constexpr CodeTab make_codes() {
    CodeTab t{};
    int n = 0;
    for (int a = 0; a < 20; ++a) {
        bool tip = (a == 4) || (a == 8) || (a == 12) || (a == 16) || (a == 19);
        int start = tip ? a + 1 : a + 2;
        for (int b = start; b < 21; ++b) {
            t.c[n] = (unsigned int)a | ((unsigned int)b << 16);
            ++n;
        }
    }
    return t;
}

__constant__ CodeTab CODES = make_codes();

__device__ __forceinline__ void scatter_tile(float* __restrict__ tile,
                                             float2* __restrict__ xy2,
                                             const f32x4 v, int t) {
    const int f = t * 4;
#pragma unroll
    for (int e = 0; e < 4; ++e) {
        const int g = f + e;
        const int row = g / 63;
        const int col = g - row * 63;
        tile[row * ROW_OUT + col] = v[e];
        const int lm = col / 3;
        const int c3 = col - lm * 3;
        if (c3 == 0) xy2[row * NLM + lm].x = v[e];
        else if (c3 == 1) xy2[row * NLM + lm].y = v[e];
    }
}

__device__ __forceinline__ void compute_dists(float* __restrict__ tile,
                                              const float2* __restrict__ xy2,
                                              int t) {
#pragma unroll
    for (int k = 0; k < 13; ++k) {
        const int idx = t + k * NTHREADS;
        if (idx < ROWS * NPAIRS) {
            const int row = idx / NPAIRS;
            const int p = idx - row * NPAIRS;
            const unsigned int c = CODES.c[p];
            const float2 a = xy2[row * NLM + (int)(c & 0xffu)];
            const float2 b = xy2[row * NLM + (int)(c >> 16)];
            const float dx = a.x - b.x;
            const float dy = a.y - b.y;
            tile[row * ROW_OUT + 63 + p] = sqrtf(dx * dx + dy * dy);
        }
    }
}

// in : [B, 63]  (21 landmarks x (x,y,z))
// out: [B, 258] = [copy of 63 | 195 pairwise 2D distances]
__global__ __launch_bounds__(NTHREADS)
void HandKineticLayer_18545668784560_kernel(const float* __restrict__ in,
                                            float* __restrict__ out,
                                            int B) {
    __shared__ __align__(16) float tile[2][TILE_F];
    __shared__ float2 xy2[2][ROWS * NLM];

    const int t = threadIdx.x;
    const int ntiles = B / ROWS;               // full tiles

    // ---- prologue: load + scatter first tile into buffer 0 ----
    const int tile0 = blockIdx.x;
    if (tile0 < ntiles) {
        if (t < 252) {
            const f32x4* __restrict__ in4 =
                reinterpret_cast<const f32x4*>(in + (size_t)tile0 * IN_F);
            const f32x4 v = __builtin_nontemporal_load(&in4[t]);
            scatter_tile(tile[0], xy2[0], v, t);
        }
        LDS_BARRIER();
    }

    // ---- pipelined main loop: prefetch(k+1) || compute(k); store(k); scatter(k+1) ----
    int i = 0;
    for (int tl = tile0; tl < ntiles; tl += GRID, ++i) {
        const int cur = i & 1;
        const int nxt = tl + GRID;
        f32x4 vn{};
        const bool have_next = (nxt < ntiles) && (t < 252);
        if (have_next) {
            const f32x4* __restrict__ in4 =
                reinterpret_cast<const f32x4*>(in + (size_t)nxt * IN_F);
            vn = __builtin_nontemporal_load(&in4[t]);   // in flight during compute+store
        }

        compute_dists(tile[cur], xy2[cur], t);
        LDS_BARRIER();     // dists visible before store reads (LDS only)

        {
            const f32x4* __restrict__ tl4 =
                reinterpret_cast<const f32x4*>(&tile[cur][0]);
            f32x4* __restrict__ o4 =
                reinterpret_cast<f32x4*>(out + (size_t)tl * TILE_F);
#pragma unroll
            for (int k = t; k < TILE_F / 4; k += NTHREADS) {
                __builtin_nontemporal_store(tl4[k], &o4[k]);
            }
        }

        if (have_next) {
            scatter_tile(tile[cur ^ 1], xy2[cur ^ 1], vn, t);
        }
        LDS_BARRIER();     // scatter visible; store's LDS reads of cur drained
    }

    // ---- tail: partial tile (B % 16 != 0), one block, non-pipelined ----
    const int rem = B - ntiles * ROWS;
    if (rem > 0 && blockIdx.x == (unsigned)(ntiles % GRID)) {
        const int rowBase = ntiles * ROWS;
        const int nelem = rem * 63;
        for (int g = t; g < nelem; g += NTHREADS) {
            const float val = in[(size_t)rowBase * 63 + g];
            const int row = g / 63;
            const int col = g - row * 63;
            tile[0][row * ROW_OUT + col] = val;
            const int lm = col / 3;
            const int c3 = col - lm * 3;
            if (c3 == 0) xy2[0][row * NLM + lm].x = val;
            else if (c3 == 1) xy2[0][row * NLM + lm].y = val;
        }
        __syncthreads();
        const int total = rem * NPAIRS;
        for (int idx = t; idx < total; idx += NTHREADS) {
            const int row = idx / NPAIRS;
            const int p = idx - row * NPAIRS;
            const unsigned int c = CODES.c[p];
            const float2 a = xy2[0][row * NLM + (int)(c & 0xffu)];
            const float2 b = xy2[0][row * NLM + (int)(c >> 16)];
            const float dx = a.x - b.x;
            const float dy = a.y - b.y;
            tile[0][row * ROW_OUT + 63 + p] = sqrtf(dx * dx + dy * dy);
        }
        __syncthreads();
        const int nout = rem * ROW_OUT;
        for (int k = t; k < nout; k += NTHREADS) {
            out[(size_t)rowBase * ROW_OUT + k] = tile[0][k];
        }
    }
}

extern "C" void kernel_launch(void* const* d_in, const int* in_sizes, int n_in,
                              void* d_out, int out_size, void* d_ws, size_t ws_size,
                              hipStream_t stream) {
    const float* in = (const float*)d_in[0];
    float* out = (float*)d_out;
    const int B = in_sizes[0] / 63;
    hipLaunchKernelGGL(HandKineticLayer_18545668784560_kernel,
                       dim3(GRID), dim3(NTHREADS), 0, stream,
                       in, out, B);
}